// Round 3
// baseline (751.060 us; speedup 1.0000x reference)
//
#include <hip/hip_runtime.h>

#define NN 4096
#define IN_F 256
#define OUT_F 64
#define K_CH 4
#define ALPHA 0.2f
#define JP 8          // j-partitions in k2 (2048 blocks -> 8 blocks/CU)
#define JCOLS 512     // NN / JP

typedef __bf16 bf16;
typedef __attribute__((ext_vector_type(8))) __bf16 bf16x8;
typedef __attribute__((ext_vector_type(4))) float f32x4;

// ---------------- k0: Wh = h@W (fp32) ; Wh1 = Wh@a[:64] ; Wh2 = Wh@a[64:]
__global__ __launch_bounds__(256) void k0_wh(const float* __restrict__ h,
                                             const float* __restrict__ W,
                                             const float* __restrict__ a,
                                             float* __restrict__ Wh,
                                             float* __restrict__ Wh1,
                                             float* __restrict__ Wh2) {
    int tid = threadIdx.x;
    int wave = tid >> 6, lane = tid & 63;
    int i = blockIdx.x * 4 + wave;
    const float* hrow = h + (size_t)i * IN_F;
    float acc = 0.f;
    #pragma unroll 8
    for (int c = 0; c < IN_F; ++c)
        acc += hrow[c] * W[c * OUT_F + lane];
    Wh[(size_t)i * OUT_F + lane] = acc;
    float v1 = acc * a[lane];
    float v2 = acc * a[OUT_F + lane];
    #pragma unroll
    for (int o = 32; o > 0; o >>= 1) {
        v1 += __shfl_xor(v1, o, 64);
        v2 += __shfl_xor(v2, o, 64);
    }
    if (lane == 0) { Wh1[i] = v1; Wh2[i] = v2; }
}

// ---------------- k0T: WhT[f][j] = (bf16)Wh[j][f]   (for MFMA B-fragments)
__global__ __launch_bounds__(256) void k0_transpose(const float* __restrict__ Wh,
                                                    bf16* __restrict__ WhT) {
    __shared__ float lds[OUT_F * 65];
    int tid = threadIdx.x;
    int i0 = blockIdx.x * 64;
    int f = tid & 63;
    int r0 = tid >> 6;
    #pragma unroll
    for (int s = 0; s < 16; ++s) {
        int r = r0 * 16 + s;
        lds[f * 65 + r] = Wh[(size_t)(i0 + r) * OUT_F + f];
    }
    __syncthreads();
    int f2 = tid >> 2;
    int c0 = (tid & 3) * 16;
    #pragma unroll
    for (int s = 0; s < 16; ++s) {
        int c = c0 + s;
        WhT[(size_t)f2 * NN + i0 + c] = (bf16)lds[f2 * 65 + c];
    }
}

// ---------------- k1: s_col[k][j] = sum_i (edge>0 ? exp(leaky(Wh1[i]+Wh2[j])*edge) : 0)
// grid (256 ichunk[16 rows], 2 jhalf, 4 k) x 256 = 2048 blocks -> 8 blocks/CU.
__global__ __launch_bounds__(256) void k1_colsum(const float* __restrict__ edge,
                                                 const float* __restrict__ Wh1,
                                                 const float* __restrict__ Wh2,
                                                 float* __restrict__ s_col) {
    int tid = threadIdx.x;
    int kch = blockIdx.z;
    int j0 = blockIdx.y * 2048 + tid * 8;
    int ibase = blockIdx.x * 16;
    float w2[8];
    {
        f32x4 t0 = *(const f32x4*)&Wh2[j0];
        f32x4 t1 = *(const f32x4*)&Wh2[j0 + 4];
        #pragma unroll
        for (int c = 0; c < 4; ++c) { w2[c] = t0[c]; w2[c + 4] = t1[c]; }
    }
    float s[8] = {0.f, 0.f, 0.f, 0.f, 0.f, 0.f, 0.f, 0.f};
    const float* base = edge + ((size_t)kch * NN + ibase) * NN + j0;
    #pragma unroll 4
    for (int ii = 0; ii < 16; ++ii) {
        float wh1 = Wh1[ibase + ii];
        f32x4 e0 = *(const f32x4*)(base + (size_t)ii * NN);
        f32x4 e1 = *(const f32x4*)(base + (size_t)ii * NN + 4);
        #pragma unroll
        for (int c = 0; c < 8; ++c) {
            float ef = c < 4 ? e0[c] : e1[c - 4];
            float xv = wh1 + w2[c];
            float lk = xv > 0.f ? xv : ALPHA * xv;
            s[c] += ef > 0.f ? __expf(lk * ef) : 0.f;
        }
    }
    #pragma unroll
    for (int c = 0; c < 8; ++c)
        atomicAdd(&s_col[kch * NN + j0 + c], s[c]);
}

// ---------------- k2: fused att computation + att write + hp = att @ Wh (MFMA)
// grid (64 itile, 4 k, 8 jp) x 256 = 2048 blocks -> 8 blocks/CU (VGPR<=64 keeps 8 waves/SIMD).
// Thread layout matches mfma_f32_16x16x32_bf16 A-fragment (row i = lane&15).
__global__ __launch_bounds__(256) void k2_fused(const float* __restrict__ edge,
                                                const float* __restrict__ Wh1,
                                                const float* __restrict__ Wh2,
                                                const float* __restrict__ s_col,
                                                const bf16* __restrict__ WhT,
                                                float* __restrict__ att_out,
                                                float* __restrict__ hp_part) {
    __shared__ float lds_inv[JCOLS];
    __shared__ float lds_w2[JCOLS];
    int tid = threadIdx.x;
    int itile = blockIdx.x;
    int kch = blockIdx.y;
    int jp = blockIdx.z;
    int jbase0 = jp * JCOLS;
    {   // per-block: 1/s and Wh2 for this j-slab into LDS
        int t2 = tid * 2;
        float s0 = s_col[kch * NN + jbase0 + t2];
        float s1 = s_col[kch * NN + jbase0 + t2 + 1];
        lds_inv[t2]     = s0 > 0.f ? 1.f / s0 : 0.f;
        lds_inv[t2 + 1] = s1 > 0.f ? 1.f / s1 : 0.f;
        lds_w2[t2]      = Wh2[jbase0 + t2];
        lds_w2[t2 + 1]  = Wh2[jbase0 + t2 + 1];
    }
    __syncthreads();
    int wave = tid >> 6, lane = tid & 63;
    int n16 = lane & 15, quad = lane >> 4;
    int i_row = itile * 64 + wave * 16 + n16;
    float wh1 = Wh1[i_row];
    const size_t erow = ((size_t)kch * NN + i_row) * (size_t)NN;
    f32x4 acc[4] = {};
    #pragma unroll 2
    for (int jt = 0; jt < JCOLS / 64; ++jt) {
        #pragma unroll
        for (int ks = 0; ks < 2; ++ks) {
            int jl = jt * 64 + ks * 32 + quad * 8;   // local j in [0,JCOLS)
            int jg = jbase0 + jl;
            f32x4 e0 = *(const f32x4*)(edge + erow + jg);
            f32x4 e1 = *(const f32x4*)(edge + erow + jg + 4);
            f32x4 iv0 = *(const f32x4*)&lds_inv[jl];
            f32x4 iv1 = *(const f32x4*)&lds_inv[jl + 4];
            f32x4 wv0 = *(const f32x4*)&lds_w2[jl];
            f32x4 wv1 = *(const f32x4*)&lds_w2[jl + 4];
            bf16x8 afrag;
            f32x4 av0, av1;
            #pragma unroll
            for (int c = 0; c < 8; ++c) {
                float ef = c < 4 ? e0[c] : e1[c - 4];
                float w2c = c < 4 ? wv0[c] : wv1[c - 4];
                float isc = c < 4 ? iv0[c] : iv1[c - 4];
                float xv = wh1 + w2c;
                float lk = xv > 0.f ? xv : ALPHA * xv;
                float attv = ef > 0.f ? __expf(lk * ef) * isc : 0.f;
                afrag[c] = (bf16)attv;
                if (c < 4) av0[c] = attv; else av1[c - 4] = attv;
            }
            *(f32x4*)(att_out + erow + jg) = av0;
            *(f32x4*)(att_out + erow + jg + 4) = av1;
            #pragma unroll
            for (int ft = 0; ft < 4; ++ft) {
                bf16x8 bfrag = *(const bf16x8*)(WhT + (size_t)(ft * 16 + n16) * NN + jg);
                acc[ft] = __builtin_amdgcn_mfma_f32_16x16x32_bf16(afrag, bfrag, acc[ft], 0, 0, 0);
            }
        }
    }
    // C/D layout: col = lane&15, row = (lane>>4)*4 + reg
    #pragma unroll
    for (int ft = 0; ft < 4; ++ft) {
        #pragma unroll
        for (int r = 0; r < 4; ++r) {
            int row_l = quad * 4 + r;
            int i_g = itile * 64 + wave * 16 + row_l;
            size_t idx = (((size_t)jp * K_CH + kch) * NN + i_g) * OUT_F + ft * 16 + n16;
            hp_part[idx] = acc[ft][r];
        }
    }
}

// ---------------- k3: out[i][k*64+f] = elu(sum_jp hp_part)
__global__ __launch_bounds__(256) void k3_combine(const float* __restrict__ hp_part,
                                                  float* __restrict__ out) {
    int g = blockIdx.x * 256 + threadIdx.x;
    int i = g >> 8;
    int rem = g & 255;
    int kch = rem >> 6;
    int f = rem & 63;
    float s = 0.f;
    #pragma unroll
    for (int z = 0; z < JP; ++z)
        s += hp_part[(((size_t)z * K_CH + kch) * NN + i) * OUT_F + f];
    out[g] = s > 0.f ? s : __expf(s) - 1.f;
}

extern "C" void kernel_launch(void* const* d_in, const int* in_sizes, int n_in,
                              void* d_out, int out_size, void* d_ws, size_t ws_size,
                              hipStream_t stream) {
    (void)out_size; (void)ws_size;
    // identify inputs by element count (all four are distinct)
    const float *h = nullptr, *edge = nullptr, *W = nullptr, *a = nullptr;
    for (int i = 0; i < n_in; ++i) {
        int sz = in_sizes[i];
        if (sz == NN * IN_F)               h    = (const float*)d_in[i];
        else if (sz == K_CH * NN * NN)     edge = (const float*)d_in[i];
        else if (sz == IN_F * OUT_F)       W    = (const float*)d_in[i];
        else if (sz == 2 * OUT_F)          a    = (const float*)d_in[i];
    }

    char* ws = (char*)d_ws;
    float* Wh    = (float*)(ws);                        // 1 MB
    float* Wh1   = (float*)(ws + 1048576);              // 16 KB
    float* Wh2   = (float*)(ws + 1048576 + 16384);      // 16 KB
    float* s_col = (float*)(ws + 1048576 + 32768);      // 64 KB
    bf16*  WhT   = (bf16*) (ws + 1048576 + 32768 + 65536);            // 512 KB
    float* hp    = (float*)(ws + 1048576 + 32768 + 65536 + 524288);   // 32 MB (JP parts)

    float* out_h   = (float*)d_out;
    float* att_out = out_h + (size_t)NN * (K_CH * OUT_F);

    hipMemsetAsync(s_col, 0, K_CH * NN * sizeof(float), stream);
    k0_wh<<<dim3(NN / 4), 256, 0, stream>>>(h, W, a, Wh, Wh1, Wh2);
    k0_transpose<<<dim3(NN / 64), 256, 0, stream>>>(Wh, WhT);
    k1_colsum<<<dim3(256, 2, 4), 256, 0, stream>>>(edge, Wh1, Wh2, s_col);
    k2_fused<<<dim3(64, 4, JP), 256, 0, stream>>>(edge, Wh1, Wh2, s_col, WhT, att_out, hp);
    k3_combine<<<dim3((NN * K_CH * OUT_F) / 256), 256, 0, stream>>>(hp, out_h);
}

// Round 4
// 629.264 us; speedup vs baseline: 1.1936x; 1.1936x over previous
//
#include <hip/hip_runtime.h>

#define NN 4096
#define IN_F 256
#define OUT_F 64
#define K_CH 4
#define ALPHA 0.2f
#define JP 8          // j-partitions in k2 (2048 blocks -> 8 blocks/CU)
#define JCOLS 512     // NN / JP
#define IC 256        // i-chunks in k1 (16 rows each)

typedef __bf16 bf16;
typedef __attribute__((ext_vector_type(8))) __bf16 bf16x8;
typedef __attribute__((ext_vector_type(4))) float f32x4;

// ---------------- k0: Wh = h@W (fp32) ; Wh1 = Wh@a[:64] ; Wh2 = Wh@a[64:]
__global__ __launch_bounds__(256) void k0_wh(const float* __restrict__ h,
                                             const float* __restrict__ W,
                                             const float* __restrict__ a,
                                             float* __restrict__ Wh,
                                             float* __restrict__ Wh1,
                                             float* __restrict__ Wh2) {
    int tid = threadIdx.x;
    int wave = tid >> 6, lane = tid & 63;
    int i = blockIdx.x * 4 + wave;
    const float* hrow = h + (size_t)i * IN_F;
    float acc = 0.f;
    #pragma unroll 8
    for (int c = 0; c < IN_F; ++c)
        acc += hrow[c] * W[c * OUT_F + lane];
    Wh[(size_t)i * OUT_F + lane] = acc;
    float v1 = acc * a[lane];
    float v2 = acc * a[OUT_F + lane];
    #pragma unroll
    for (int o = 32; o > 0; o >>= 1) {
        v1 += __shfl_xor(v1, o, 64);
        v2 += __shfl_xor(v2, o, 64);
    }
    if (lane == 0) { Wh1[i] = v1; Wh2[i] = v2; }
}

// ---------------- k0T: WhT[f][j] = (bf16)Wh[j][f]   (for MFMA B-fragments)
__global__ __launch_bounds__(256) void k0_transpose(const float* __restrict__ Wh,
                                                    bf16* __restrict__ WhT) {
    __shared__ float lds[OUT_F * 65];
    int tid = threadIdx.x;
    int i0 = blockIdx.x * 64;
    int f = tid & 63;
    int r0 = tid >> 6;
    #pragma unroll
    for (int s = 0; s < 16; ++s) {
        int r = r0 * 16 + s;
        lds[f * 65 + r] = Wh[(size_t)(i0 + r) * OUT_F + f];
    }
    __syncthreads();
    int f2 = tid >> 2;
    int c0 = (tid & 3) * 16;
    #pragma unroll
    for (int s = 0; s < 16; ++s) {
        int c = c0 + s;
        WhT[(size_t)f2 * NN + i0 + c] = (bf16)lds[f2 * 65 + c];
    }
}

// ---------------- k1: per-block partial column sums (NO atomics)
// partial[ic][k][j] = sum_{i in chunk ic} (edge>0 ? exp(leaky(Wh1[i]+Wh2[j])*edge) : 0)
// grid (256 ichunk[16 rows], 2 jhalf, 4 k) x 256 = 2048 blocks -> 8 blocks/CU.
__global__ __launch_bounds__(256) void k1_colsum(const float* __restrict__ edge,
                                                 const float* __restrict__ Wh1,
                                                 const float* __restrict__ Wh2,
                                                 float* __restrict__ partial) {
    int tid = threadIdx.x;
    int kch = blockIdx.z;
    int j0 = blockIdx.y * 2048 + tid * 8;
    int ic = blockIdx.x;
    int ibase = ic * 16;
    float w2[8];
    {
        f32x4 t0 = *(const f32x4*)&Wh2[j0];
        f32x4 t1 = *(const f32x4*)&Wh2[j0 + 4];
        #pragma unroll
        for (int c = 0; c < 4; ++c) { w2[c] = t0[c]; w2[c + 4] = t1[c]; }
    }
    float s[8] = {0.f, 0.f, 0.f, 0.f, 0.f, 0.f, 0.f, 0.f};
    const float* base = edge + ((size_t)kch * NN + ibase) * NN + j0;
    #pragma unroll 4
    for (int ii = 0; ii < 16; ++ii) {
        float wh1 = Wh1[ibase + ii];
        f32x4 e0 = *(const f32x4*)(base + (size_t)ii * NN);
        f32x4 e1 = *(const f32x4*)(base + (size_t)ii * NN + 4);
        #pragma unroll
        for (int c = 0; c < 8; ++c) {
            float ef = c < 4 ? e0[c] : e1[c - 4];
            float xv = wh1 + w2[c];
            float lk = xv > 0.f ? xv : ALPHA * xv;
            s[c] += ef > 0.f ? __expf(lk * ef) : 0.f;
        }
    }
    float* pr = partial + ((size_t)ic * K_CH + kch) * NN + j0;
    f32x4 o0, o1;
    #pragma unroll
    for (int c = 0; c < 4; ++c) { o0[c] = s[c]; o1[c] = s[c + 4]; }
    *(f32x4*)pr = o0;
    *(f32x4*)(pr + 4) = o1;
}

// ---------------- k1b: s_col[g] = sum_ic partial[ic][g],  g = k*NN+j
__global__ __launch_bounds__(256) void k1_reduce(const float* __restrict__ partial,
                                                 float* __restrict__ s_col) {
    int g = blockIdx.x * 256 + threadIdx.x;
    float s = 0.f;
    #pragma unroll 8
    for (int ic = 0; ic < IC; ++ic)
        s += partial[(size_t)ic * (K_CH * NN) + g];
    s_col[g] = s;
}

// ---------------- k2: fused att computation + att write + hp = att @ Wh (MFMA)
// grid (64 itile, 4 k, 8 jp) x 256 = 2048 blocks -> 8 blocks/CU.
// Thread layout matches mfma_f32_16x16x32_bf16 A-fragment (row i = lane&15).
__global__ __launch_bounds__(256) void k2_fused(const float* __restrict__ edge,
                                                const float* __restrict__ Wh1,
                                                const float* __restrict__ Wh2,
                                                const float* __restrict__ s_col,
                                                const bf16* __restrict__ WhT,
                                                float* __restrict__ att_out,
                                                float* __restrict__ hp_part) {
    __shared__ float lds_inv[JCOLS];
    __shared__ float lds_w2[JCOLS];
    int tid = threadIdx.x;
    int itile = blockIdx.x;
    int kch = blockIdx.y;
    int jp = blockIdx.z;
    int jbase0 = jp * JCOLS;
    {   // per-block: 1/s and Wh2 for this j-slab into LDS
        int t2 = tid * 2;
        float s0 = s_col[kch * NN + jbase0 + t2];
        float s1 = s_col[kch * NN + jbase0 + t2 + 1];
        lds_inv[t2]     = s0 > 0.f ? 1.f / s0 : 0.f;
        lds_inv[t2 + 1] = s1 > 0.f ? 1.f / s1 : 0.f;
        lds_w2[t2]      = Wh2[jbase0 + t2];
        lds_w2[t2 + 1]  = Wh2[jbase0 + t2 + 1];
    }
    __syncthreads();
    int wave = tid >> 6, lane = tid & 63;
    int n16 = lane & 15, quad = lane >> 4;
    int i_row = itile * 64 + wave * 16 + n16;
    float wh1 = Wh1[i_row];
    const size_t erow = ((size_t)kch * NN + i_row) * (size_t)NN;
    f32x4 acc[4] = {};
    #pragma unroll 2
    for (int jt = 0; jt < JCOLS / 64; ++jt) {
        #pragma unroll
        for (int ks = 0; ks < 2; ++ks) {
            int jl = jt * 64 + ks * 32 + quad * 8;   // local j in [0,JCOLS)
            int jg = jbase0 + jl;
            f32x4 e0 = *(const f32x4*)(edge + erow + jg);
            f32x4 e1 = *(const f32x4*)(edge + erow + jg + 4);
            f32x4 iv0 = *(const f32x4*)&lds_inv[jl];
            f32x4 iv1 = *(const f32x4*)&lds_inv[jl + 4];
            f32x4 wv0 = *(const f32x4*)&lds_w2[jl];
            f32x4 wv1 = *(const f32x4*)&lds_w2[jl + 4];
            bf16x8 afrag;
            f32x4 av0, av1;
            #pragma unroll
            for (int c = 0; c < 8; ++c) {
                float ef = c < 4 ? e0[c] : e1[c - 4];
                float w2c = c < 4 ? wv0[c] : wv1[c - 4];
                float isc = c < 4 ? iv0[c] : iv1[c - 4];
                float xv = wh1 + w2c;
                float lk = xv > 0.f ? xv : ALPHA * xv;
                float attv = ef > 0.f ? __expf(lk * ef) * isc : 0.f;
                afrag[c] = (bf16)attv;
                if (c < 4) av0[c] = attv; else av1[c - 4] = attv;
            }
            *(f32x4*)(att_out + erow + jg) = av0;
            *(f32x4*)(att_out + erow + jg + 4) = av1;
            #pragma unroll
            for (int ft = 0; ft < 4; ++ft) {
                bf16x8 bfrag = *(const bf16x8*)(WhT + (size_t)(ft * 16 + n16) * NN + jg);
                acc[ft] = __builtin_amdgcn_mfma_f32_16x16x32_bf16(afrag, bfrag, acc[ft], 0, 0, 0);
            }
        }
    }
    // C/D layout: col = lane&15, row = (lane>>4)*4 + reg
    #pragma unroll
    for (int ft = 0; ft < 4; ++ft) {
        #pragma unroll
        for (int r = 0; r < 4; ++r) {
            int row_l = quad * 4 + r;
            int i_g = itile * 64 + wave * 16 + row_l;
            size_t idx = (((size_t)jp * K_CH + kch) * NN + i_g) * OUT_F + ft * 16 + n16;
            hp_part[idx] = acc[ft][r];
        }
    }
}

// ---------------- k3: out[i][k*64+f] = elu(sum_jp hp_part)
__global__ __launch_bounds__(256) void k3_combine(const float* __restrict__ hp_part,
                                                  float* __restrict__ out) {
    int g = blockIdx.x * 256 + threadIdx.x;
    int i = g >> 8;
    int rem = g & 255;
    int kch = rem >> 6;
    int f = rem & 63;
    float s = 0.f;
    #pragma unroll
    for (int z = 0; z < JP; ++z)
        s += hp_part[(((size_t)z * K_CH + kch) * NN + i) * OUT_F + f];
    out[g] = s > 0.f ? s : __expf(s) - 1.f;
}

extern "C" void kernel_launch(void* const* d_in, const int* in_sizes, int n_in,
                              void* d_out, int out_size, void* d_ws, size_t ws_size,
                              hipStream_t stream) {
    (void)out_size; (void)ws_size;
    // identify inputs by element count (all four are distinct)
    const float *h = nullptr, *edge = nullptr, *W = nullptr, *a = nullptr;
    for (int i = 0; i < n_in; ++i) {
        int sz = in_sizes[i];
        if (sz == NN * IN_F)               h    = (const float*)d_in[i];
        else if (sz == K_CH * NN * NN)     edge = (const float*)d_in[i];
        else if (sz == IN_F * OUT_F)       W    = (const float*)d_in[i];
        else if (sz == 2 * OUT_F)          a    = (const float*)d_in[i];
    }

    char* ws = (char*)d_ws;
    float* Wh    = (float*)(ws);                        // 1 MB
    float* Wh1   = (float*)(ws + 1048576);              // 16 KB
    float* Wh2   = (float*)(ws + 1048576 + 16384);      // 16 KB
    float* s_col = (float*)(ws + 1048576 + 32768);      // 64 KB
    bf16*  WhT   = (bf16*) (ws + 1048576 + 32768 + 65536);            // 512 KB
    float* hp    = (float*)(ws + 1048576 + 32768 + 65536 + 524288);   // 32 MB (JP parts)
    // k1 partials (16 MB) alias the hp region: consumed by k1_reduce BEFORE
    // k2 writes hp (same-stream ordering). No extra workspace needed.
    float* partial = hp;

    float* out_h   = (float*)d_out;
    float* att_out = out_h + (size_t)NN * (K_CH * OUT_F);

    k0_wh<<<dim3(NN / 4), 256, 0, stream>>>(h, W, a, Wh, Wh1, Wh2);
    k0_transpose<<<dim3(NN / 64), 256, 0, stream>>>(Wh, WhT);
    k1_colsum<<<dim3(IC, 2, 4), 256, 0, stream>>>(edge, Wh1, Wh2, partial);
    k1_reduce<<<dim3(K_CH * NN / 256), 256, 0, stream>>>(partial, s_col);
    k2_fused<<<dim3(64, 4, JP), 256, 0, stream>>>(edge, Wh1, Wh2, s_col, WhT, att_out, hp);
    k3_combine<<<dim3((NN * K_CH * OUT_F) / 256), 256, 0, stream>>>(hp, out_h);
}

// Round 5
// 617.572 us; speedup vs baseline: 1.2162x; 1.0189x over previous
//
#include <hip/hip_runtime.h>

#define NN 4096
#define IN_F 256
#define OUT_F 64
#define K_CH 4
#define ALPHA 0.2f
#define JP 8          // j-partitions in k2 (2048 blocks -> 8 blocks/CU)
#define JCOLS 512     // NN / JP
#define IC 256        // i-chunks in k1 (16 rows each)

typedef __bf16 bf16;
typedef __attribute__((ext_vector_type(8))) __bf16 bf16x8;
typedef __attribute__((ext_vector_type(4))) float f32x4;

// ---------------- k0: Wh = h@W (fp32) ; Wh1 = Wh@a[:64] ; Wh2 = Wh@a[64:]
__global__ __launch_bounds__(256) void k0_wh(const float* __restrict__ h,
                                             const float* __restrict__ W,
                                             const float* __restrict__ a,
                                             float* __restrict__ Wh,
                                             float* __restrict__ Wh1,
                                             float* __restrict__ Wh2) {
    int tid = threadIdx.x;
    int wave = tid >> 6, lane = tid & 63;
    int i = blockIdx.x * 4 + wave;
    const float* hrow = h + (size_t)i * IN_F;
    float acc = 0.f;
    #pragma unroll 8
    for (int c = 0; c < IN_F; ++c)
        acc += hrow[c] * W[c * OUT_F + lane];
    Wh[(size_t)i * OUT_F + lane] = acc;
    float v1 = acc * a[lane];
    float v2 = acc * a[OUT_F + lane];
    #pragma unroll
    for (int o = 32; o > 0; o >>= 1) {
        v1 += __shfl_xor(v1, o, 64);
        v2 += __shfl_xor(v2, o, 64);
    }
    if (lane == 0) { Wh1[i] = v1; Wh2[i] = v2; }
}

// ---------------- k0T: WhT[f][j] = (bf16)Wh[j][f]   (for MFMA B-fragments)
__global__ __launch_bounds__(256) void k0_transpose(const float* __restrict__ Wh,
                                                    bf16* __restrict__ WhT) {
    __shared__ float lds[OUT_F * 65];
    int tid = threadIdx.x;
    int i0 = blockIdx.x * 64;
    int f = tid & 63;
    int r0 = tid >> 6;
    #pragma unroll
    for (int s = 0; s < 16; ++s) {
        int r = r0 * 16 + s;
        lds[f * 65 + r] = Wh[(size_t)(i0 + r) * OUT_F + f];
    }
    __syncthreads();
    int f2 = tid >> 2;
    int c0 = (tid & 3) * 16;
    #pragma unroll
    for (int s = 0; s < 16; ++s) {
        int c = c0 + s;
        WhT[(size_t)f2 * NN + i0 + c] = (bf16)lds[f2 * 65 + c];
    }
}

// ---------------- k1: per-block partial column sums (no atomics),
// with depth-2 row prefetch pipeline for memory-level parallelism.
// grid (256 ichunk[16 rows], 2 jhalf, 4 k) x 256.
__global__ __launch_bounds__(256) void k1_colsum(const float* __restrict__ edge,
                                                 const float* __restrict__ Wh1,
                                                 const float* __restrict__ Wh2,
                                                 float* __restrict__ partial) {
    int tid = threadIdx.x;
    int kch = blockIdx.z;
    int j0 = blockIdx.y * 2048 + tid * 8;
    int ic = blockIdx.x;
    int ibase = ic * 16;
    float w2[8];
    {
        f32x4 t0 = *(const f32x4*)&Wh2[j0];
        f32x4 t1 = *(const f32x4*)&Wh2[j0 + 4];
        #pragma unroll
        for (int c = 0; c < 4; ++c) { w2[c] = t0[c]; w2[c + 4] = t1[c]; }
    }
    float s[8] = {0.f, 0.f, 0.f, 0.f, 0.f, 0.f, 0.f, 0.f};
    const float* base = edge + ((size_t)kch * NN + ibase) * NN + j0;
    // prefetch rows 0,1
    f32x4 r0[2], r1[2];
    r0[0] = *(const f32x4*)(base);
    r1[0] = *(const f32x4*)(base + 4);
    r0[1] = *(const f32x4*)(base + NN);
    r1[1] = *(const f32x4*)(base + NN + 4);
    #pragma unroll 2
    for (int ii = 0; ii < 16; ++ii) {
        int cur = ii & 1;
        f32x4 e0 = r0[cur], e1 = r1[cur];
        int ip = (ii + 2 < 16) ? ii + 2 : ii;      // clamp: harmless reload
        r0[cur] = *(const f32x4*)(base + (size_t)ip * NN);
        r1[cur] = *(const f32x4*)(base + (size_t)ip * NN + 4);
        float wh1 = Wh1[ibase + ii];
        #pragma unroll
        for (int c = 0; c < 8; ++c) {
            float ef = c < 4 ? e0[c] : e1[c - 4];
            float xv = wh1 + w2[c];
            float lk = xv > 0.f ? xv : ALPHA * xv;
            s[c] += ef > 0.f ? __expf(lk * ef) : 0.f;
        }
    }
    float* pr = partial + ((size_t)ic * K_CH + kch) * NN + j0;
    f32x4 o0, o1;
    #pragma unroll
    for (int c = 0; c < 4; ++c) { o0[c] = s[c]; o1[c] = s[c + 4]; }
    *(f32x4*)pr = o0;
    *(f32x4*)(pr + 4) = o1;
}

// ---------------- k1b: s_col[g] = sum_ic partial[ic][g],  g = k*NN+j
__global__ __launch_bounds__(256) void k1_reduce(const float* __restrict__ partial,
                                                 float* __restrict__ s_col) {
    int g = blockIdx.x * 256 + threadIdx.x;
    float s = 0.f;
    #pragma unroll 8
    for (int ic = 0; ic < IC; ++ic)
        s += partial[(size_t)ic * (K_CH * NN) + g];
    s_col[g] = s;
}

// ---------------- k2: fused att + att write (nontemporal) + hp = att @ Wh (MFMA),
// with depth-2 step prefetch pipeline.
// grid (64 itile, 4 k, 8 jp) x 256. Wave layout = mfma A-fragment.
__global__ __launch_bounds__(256) void k2_fused(const float* __restrict__ edge,
                                                const float* __restrict__ Wh1,
                                                const float* __restrict__ Wh2,
                                                const float* __restrict__ s_col,
                                                const bf16* __restrict__ WhT,
                                                float* __restrict__ att_out,
                                                float* __restrict__ hp_part) {
    __shared__ float lds_inv[JCOLS];
    __shared__ float lds_w2[JCOLS];
    int tid = threadIdx.x;
    int itile = blockIdx.x;
    int kch = blockIdx.y;
    int jp = blockIdx.z;
    int jbase0 = jp * JCOLS;
    {   // per-block: 1/s and Wh2 for this j-slab into LDS
        int t2 = tid * 2;
        float s0 = s_col[kch * NN + jbase0 + t2];
        float s1 = s_col[kch * NN + jbase0 + t2 + 1];
        lds_inv[t2]     = s0 > 0.f ? 1.f / s0 : 0.f;
        lds_inv[t2 + 1] = s1 > 0.f ? 1.f / s1 : 0.f;
        lds_w2[t2]      = Wh2[jbase0 + t2];
        lds_w2[t2 + 1]  = Wh2[jbase0 + t2 + 1];
    }
    __syncthreads();
    int wave = tid >> 6, lane = tid & 63;
    int n16 = lane & 15, quad = lane >> 4;
    int i_row = itile * 64 + wave * 16 + n16;
    float wh1 = Wh1[i_row];
    const size_t ebase = ((size_t)kch * NN + i_row) * (size_t)NN + jbase0 + quad * 8;
    const float* eptr = edge + ebase;
    float* aptr = att_out + ebase;
    const bf16* wbase = WhT + (size_t)n16 * NN + jbase0 + quad * 8;
    f32x4 acc[4] = {};
    // prefetch steps 0,1  (step s covers local j = s*32 + quad*8 .. +7)
    f32x4 p0[2], p1[2];
    #pragma unroll
    for (int t = 0; t < 2; ++t) {
        p0[t] = *(const f32x4*)(eptr + t * 32);
        p1[t] = *(const f32x4*)(eptr + t * 32 + 4);
    }
    #pragma unroll 2
    for (int s = 0; s < 16; ++s) {
        int cur = s & 1;
        f32x4 e0 = p0[cur], e1 = p1[cur];
        int sp = (s + 2 < 16) ? s + 2 : s;          // clamp: harmless reload
        p0[cur] = *(const f32x4*)(eptr + sp * 32);
        p1[cur] = *(const f32x4*)(eptr + sp * 32 + 4);
        int jl = s * 32 + quad * 8;                 // local j of this lane's 8 cols
        f32x4 iv0 = *(const f32x4*)&lds_inv[jl];
        f32x4 iv1 = *(const f32x4*)&lds_inv[jl + 4];
        f32x4 wv0 = *(const f32x4*)&lds_w2[jl];
        f32x4 wv1 = *(const f32x4*)&lds_w2[jl + 4];
        bf16x8 afrag;
        f32x4 av0, av1;
        #pragma unroll
        for (int c = 0; c < 8; ++c) {
            float ef = c < 4 ? e0[c] : e1[c - 4];
            float w2c = c < 4 ? wv0[c] : wv1[c - 4];
            float isc = c < 4 ? iv0[c] : iv1[c - 4];
            float xv = wh1 + w2c;
            float lk = xv > 0.f ? xv : ALPHA * xv;
            float attv = ef > 0.f ? __expf(lk * ef) * isc : 0.f;
            afrag[c] = (bf16)attv;
            if (c < 4) av0[c] = attv; else av1[c - 4] = attv;
        }
        __builtin_nontemporal_store(av0, (f32x4*)(aptr + s * 32));
        __builtin_nontemporal_store(av1, (f32x4*)(aptr + s * 32 + 4));
        #pragma unroll
        for (int ft = 0; ft < 4; ++ft) {
            bf16x8 bfrag = *(const bf16x8*)(wbase + (size_t)ft * 16 * NN + s * 32);
            acc[ft] = __builtin_amdgcn_mfma_f32_16x16x32_bf16(afrag, bfrag, acc[ft], 0, 0, 0);
        }
    }
    // C/D layout: col = lane&15, row = (lane>>4)*4 + reg
    #pragma unroll
    for (int ft = 0; ft < 4; ++ft) {
        #pragma unroll
        for (int r = 0; r < 4; ++r) {
            int row_l = quad * 4 + r;
            int i_g = itile * 64 + wave * 16 + row_l;
            size_t idx = (((size_t)jp * K_CH + kch) * NN + i_g) * OUT_F + ft * 16 + n16;
            hp_part[idx] = acc[ft][r];
        }
    }
}

// ---------------- k3: out[i][k*64+f] = elu(sum_jp hp_part)
__global__ __launch_bounds__(256) void k3_combine(const float* __restrict__ hp_part,
                                                  float* __restrict__ out) {
    int g = blockIdx.x * 256 + threadIdx.x;
    int i = g >> 8;
    int rem = g & 255;
    int kch = rem >> 6;
    int f = rem & 63;
    float s = 0.f;
    #pragma unroll
    for (int z = 0; z < JP; ++z)
        s += hp_part[(((size_t)z * K_CH + kch) * NN + i) * OUT_F + f];
    out[g] = s > 0.f ? s : __expf(s) - 1.f;
}

extern "C" void kernel_launch(void* const* d_in, const int* in_sizes, int n_in,
                              void* d_out, int out_size, void* d_ws, size_t ws_size,
                              hipStream_t stream) {
    (void)out_size; (void)ws_size;
    // identify inputs by element count (all four are distinct)
    const float *h = nullptr, *edge = nullptr, *W = nullptr, *a = nullptr;
    for (int i = 0; i < n_in; ++i) {
        int sz = in_sizes[i];
        if (sz == NN * IN_F)               h    = (const float*)d_in[i];
        else if (sz == K_CH * NN * NN)     edge = (const float*)d_in[i];
        else if (sz == IN_F * OUT_F)       W    = (const float*)d_in[i];
        else if (sz == 2 * OUT_F)          a    = (const float*)d_in[i];
    }

    char* ws = (char*)d_ws;
    float* Wh    = (float*)(ws);                        // 1 MB
    float* Wh1   = (float*)(ws + 1048576);              // 16 KB
    float* Wh2   = (float*)(ws + 1048576 + 16384);      // 16 KB
    float* s_col = (float*)(ws + 1048576 + 32768);      // 64 KB
    bf16*  WhT   = (bf16*) (ws + 1048576 + 32768 + 65536);            // 512 KB
    float* hp    = (float*)(ws + 1048576 + 32768 + 65536 + 524288);   // 32 MB (JP parts)
    // k1 partials (16 MB) alias the hp region: consumed by k1_reduce BEFORE
    // k2 writes hp (same-stream ordering). No extra workspace needed.
    float* partial = hp;

    float* out_h   = (float*)d_out;
    float* att_out = out_h + (size_t)NN * (K_CH * OUT_F);

    k0_wh<<<dim3(NN / 4), 256, 0, stream>>>(h, W, a, Wh, Wh1, Wh2);
    k0_transpose<<<dim3(NN / 64), 256, 0, stream>>>(Wh, WhT);
    k1_colsum<<<dim3(IC, 2, 4), 256, 0, stream>>>(edge, Wh1, Wh2, partial);
    k1_reduce<<<dim3(K_CH * NN / 256), 256, 0, stream>>>(partial, s_col);
    k2_fused<<<dim3(64, 4, JP), 256, 0, stream>>>(edge, Wh1, Wh2, s_col, WhT, att_out, hp);
    k3_combine<<<dim3((NN * K_CH * OUT_F) / 256), 256, 0, stream>>>(hp, out_h);
}